// Round 4
// baseline (202.166 us; speedup 1.0000x reference)
//
#include <hip/hip_runtime.h>
#include <math.h>

#define NN   10000
#define DEG  16
#define SS   128
#define NRBF 20
#define GG   64
#define RC   10.0f
#define PI_F 3.14159265358979323846f
#define NB   8

__device__ __forceinline__ float silu_f(float x){
    return x / (1.0f + __expf(-x));
}

// ---------------------------------------------------------------------------
// Kernel 1a: h = silu(s0 @ phi_w1 + b1)  (s0 uniform). Also zeroes gs.
// ---------------------------------------------------------------------------
__global__ __launch_bounds__(256) void k_phi1(
    const float* __restrict__ emb0,
    const float* __restrict__ w1, const float* __restrict__ b1,
    float* __restrict__ phiH, float* __restrict__ gs){
    __shared__ float s0[SS];
    __shared__ float part[2][SS];
    int t = threadIdx.x;
    for (int i = t; i < GG*SS; i += 256) gs[i] = 0.0f;
    if (t < SS) s0[t] = 128.0f * emb0[t];
    __syncthreads();
    int c = t & 127, half = t >> 7;
    float acc = 0.0f;
    int s0i = half * 64;
    #pragma unroll 8
    for (int s = 0; s < 64; s++)
        acc = fmaf(s0[s0i + s], w1[(s0i + s)*SS + c], acc);
    part[half][c] = acc;
    __syncthreads();
    if (t < SS) phiH[t] = silu_f(b1[t] + part[0][t] + part[1][t]);
}

// ---------------------------------------------------------------------------
// Kernel 1b: phiW = h @ phi_w2 + b2. 12 blocks x 128 threads, split-K 4-way.
// ---------------------------------------------------------------------------
__global__ __launch_bounds__(128) void k_phi2(
    const float* __restrict__ phiH,
    const float* __restrict__ w2, const float* __restrict__ b2,
    float* __restrict__ phiW){
    __shared__ float hL[SS];
    __shared__ float part[4][32];
    int t = threadIdx.x;
    hL[t] = phiH[t];
    __syncthreads();
    int c  = blockIdx.x*32 + (t & 31);
    int kk = t >> 5;
    float acc = 0.0f;
    int sbase = kk * 32;
    #pragma unroll 8
    for (int s = 0; s < 32; s++)
        acc = fmaf(hL[sbase + s], w2[(sbase + s)*3*SS + c], acc);
    part[kk][t & 31] = acc;
    __syncthreads();
    if (t < 32){
        int cc = blockIdx.x*32 + t;
        phiW[cc] = b2[cc] + part[0][t] + part[1][t] + part[2][t] + part[3][t];
    }
}

// ---------------------------------------------------------------------------
// Kernel 2: per-node edge processing, 64 threads/block (ONE wave).
// Thread t computes 4 channels: m2 {128+t, 192+t} -> state,
// m3 {256+t, 320+t} -> sv. One wave per block halves the duplicated
// rbf LDS broadcast instructions vs the 2-wave version.
// ---------------------------------------------------------------------------
__global__ __launch_bounds__(64) void k_edge(
    const float* __restrict__ evd, const float* __restrict__ elen,
    const int* __restrict__ node_from,
    const float* __restrict__ filt_w, const float* __restrict__ filt_b,
    const float* __restrict__ phiW,
    float* __restrict__ state, float* __restrict__ sv){
    __shared__ float rS[DEG];
    __shared__ float mcL[DEG];
    __shared__ float frL[DEG];
    __shared__ float eV[DEG][3];
    __shared__ float rbfL[DEG][NRBF];
    __shared__ float invD;
    int n = blockIdx.x;
    int t = threadIdx.x;

    if (t < DEG){
        int e = n*DEG + t;
        float x = evd[3*e+0], y = evd[3*e+1], z = evd[3*e+2];
        float r = sqrtf(x*x + y*y + z*z);
        float len  = elen[e];
        float mask = (fabsf(len) <= RC) ? 1.0f : 0.0f;
        float cut  = (r < RC) ? 0.5f*(cosf(PI_F*r*(1.0f/RC)) + 1.0f) : 0.0f;
        rS[t]  = fmaxf(r, 1e-12f);
        mcL[t] = mask * cut;
        frL[t] = mask * r * r;
        eV[t][0] = x; eV[t][1] = y; eV[t][2] = z;
    }
    __syncthreads();
    for (int idx = t; idx < DEG*NRBF; idx += 64){
        int e = idx / NRBF, k = idx % NRBF;
        float rs = rS[e];
        rbfL[e][k] = sinf((float)(k+1) * (PI_F/RC) * rs) / rs;
    }
    if (t == 0){
        float s = 0.0f;
        for (int e = 0; e < DEG; e++) s += frL[e];
        float fbn = sqrtf(s);
        invD = (fbn > 0.0f) ? 1.0f/fbn : 1.0f;
    }
    __syncthreads();

    // 4 channels per thread
    int gcA = SS + t, gcB = SS + 64 + t;       // m2
    int gcC = 2*SS + t, gcD = 2*SS + 64 + t;   // m3
    float fwA[NRBF], fwB[NRBF], fwC[NRBF], fwD[NRBF];
    #pragma unroll
    for (int k = 0; k < NRBF; k++){
        fwA[k] = filt_w[k*(3*SS) + gcA];
        fwB[k] = filt_w[k*(3*SS) + gcB];
        fwC[k] = filt_w[k*(3*SS) + gcC];
        fwD[k] = filt_w[k*(3*SS) + gcD];
    }
    float fbA = filt_b[gcA], fbB = filt_b[gcB];
    float fbC = filt_b[gcC], fbD = filt_b[gcD];
    float phA = phiW[gcA], phB = phiW[gcB];
    float phC = phiW[gcC], phD = phiW[gcD];
    float iD  = invD;
    int   s3C = t % 3;
    int   s3D = (t + 64) % 3;

    float accA = 0.f, accB = 0.f, accC = 0.f, accD = 0.f;
    for (int e = 0; e < DEG; e++){
        float mc = mcL[e];
        if (mc == 0.0f) continue;   // wave-uniform
        const float4* rv = (const float4*)(&rbfL[e][0]);
        float4 r0 = rv[0], r1 = rv[1], r2 = rv[2], r3 = rv[3], r4 = rv[4];
        float rr[20] = {r0.x,r0.y,r0.z,r0.w, r1.x,r1.y,r1.z,r1.w,
                        r2.x,r2.y,r2.z,r2.w, r3.x,r3.y,r3.z,r3.w,
                        r4.x,r4.y,r4.z,r4.w};
        float wA = fbA, wB = fbB, wC = fbC, wD = fbD;
        #pragma unroll
        for (int k = 0; k < NRBF; k++){
            wA = fmaf(rr[k], fwA[k], wA);
            wB = fmaf(rr[k], fwB[k], wB);
            wC = fmaf(rr[k], fwC[k], wC);
            wD = fmaf(rr[k], fwD[k], wD);
        }
        accA = fmaf(phA*mc, wA, accA);
        accB = fmaf(phB*mc, wB, accB);
        accC = fmaf(phC*mc*eV[e][s3C]*iD, wC, accC);
        accD = fmaf(phD*mc*eV[e][s3D]*iD, wD, accD);
    }
    int nf = node_from[n*DEG];
    state[nf*SS + t]      = accA;
    state[nf*SS + 64 + t] = accB;
    sv[nf*SS + t]         = accC;
    sv[nf*SS + 64 + t]    = accD;
}

// ---------------------------------------------------------------------------
// Kernel 3: per-node update, NB=8 nodes / 128-thread block.
// Lane l of wave w handles channels {2l, 2l+1}, nodes {4w..4w+3}.
// One ds_read_b128 broadcast per matvec row per wave (halved vs before).
// ---------------------------------------------------------------------------
__global__ __launch_bounds__(128) void k_update(
    const float* __restrict__ state, const float* __restrict__ sv,
    const float* __restrict__ u_w, const float* __restrict__ v_w,
    const float* __restrict__ upd_w1, const float* __restrict__ upd_b1,
    const float* __restrict__ upd_w2, const float* __restrict__ upd_b2,
    const int* __restrict__ ngi, float* __restrict__ gs){
    __shared__ float svT[SS][NB];     // phase A: sv rows; phase B writes h here
    __shared__ float xT[2*SS][NB];    // rows 0..127 Vnorm, 128..255 state
    __shared__ float dL[NB];
    __shared__ int   gIdx[NB];
    int t  = threadIdx.x;
    int w  = t >> 6, l = t & 63;
    int c0 = 2*l;         // channels c0, c0+1
    int b0 = 4*w;         // nodes b0..b0+3
    int n0 = blockIdx.x * NB;

    if (t < NB) gIdx[t] = ngi[n0 + t];
    for (int idx = t; idx < NB*SS; idx += 128){
        int b = idx >> 7, s = idx & (SS-1);
        svT[s][b]   = sv[(n0+b)*SS + s];
        xT[SS+s][b] = state[(n0+b)*SS + s];
    }
    __syncthreads();

    // Phase A: U,V for (nodes b0.., channels c0..)
    float accU[2][4], accV[2][4];
    #pragma unroll
    for (int j = 0; j < 2; j++)
        #pragma unroll
        for (int k = 0; k < 4; k++){ accU[j][k] = 0.f; accV[j][k] = 0.f; }
    #pragma unroll 4
    for (int i = 0; i < SS; i++){
        float4 xv = *(const float4*)(&svT[i][b0]);
        float2 wu = *(const float2*)(u_w + i*SS + c0);
        float2 wv = *(const float2*)(v_w + i*SS + c0);
        float xa[4] = {xv.x, xv.y, xv.z, xv.w};
        #pragma unroll
        for (int k = 0; k < 4; k++){
            accU[0][k] = fmaf(xa[k], wu.x, accU[0][k]);
            accU[1][k] = fmaf(xa[k], wu.y, accU[1][k]);
            accV[0][k] = fmaf(xa[k], wv.x, accV[0][k]);
            accV[1][k] = fmaf(xa[k], wv.y, accV[1][k]);
        }
    }

    // d[b] = sum over channels (wave-local: this wave covers all 128 ch)
    float pd[4];
    #pragma unroll
    for (int k = 0; k < 4; k++)
        pd[k] = accU[0][k]*accV[0][k] + accU[1][k]*accV[1][k];
    #pragma unroll
    for (int off = 32; off; off >>= 1){
        #pragma unroll
        for (int k = 0; k < 4; k++) pd[k] += __shfl_down(pd[k], off);
    }
    if (l == 0){
        #pragma unroll
        for (int k = 0; k < 4; k++) dL[b0+k] = pd[k];
    }
    // Vnorm rows 0..127 of xT
    const float SQ3 = 1.7320508075688772f;
    #pragma unroll
    for (int j = 0; j < 2; j++)
        #pragma unroll
        for (int k = 0; k < 4; k++)
            xT[c0+j][b0+k] = SQ3 * fabsf(accV[j][k]);
    __syncthreads();

    float dreg[4];
    #pragma unroll
    for (int k = 0; k < 4; k++) dreg[k] = dL[b0+k];

    // Phase B: h = silu([Vnorm,state] @ upd_w1 + b1)
    float accH[2][4];
    #pragma unroll
    for (int j = 0; j < 2; j++)
        #pragma unroll
        for (int k = 0; k < 4; k++) accH[j][k] = 0.f;
    #pragma unroll 4
    for (int i = 0; i < 2*SS; i++){
        float4 xv = *(const float4*)(&xT[i][b0]);
        float2 ww = *(const float2*)(upd_w1 + i*SS + c0);
        float xa[4] = {xv.x, xv.y, xv.z, xv.w};
        #pragma unroll
        for (int k = 0; k < 4; k++){
            accH[0][k] = fmaf(xa[k], ww.x, accH[0][k]);
            accH[1][k] = fmaf(xa[k], ww.y, accH[1][k]);
        }
    }
    {
        float2 b1v = *(const float2*)(upd_b1 + c0);
        #pragma unroll
        for (int k = 0; k < 4; k++){
            svT[c0+0][b0+k] = silu_f(accH[0][k] + b1v.x);
            svT[c0+1][b0+k] = silu_f(accH[1][k] + b1v.y);
        }
    }
    __syncthreads();

    // Phase C: a_sv, a_ss
    float a2[2][4], a3[2][4];
    #pragma unroll
    for (int j = 0; j < 2; j++)
        #pragma unroll
        for (int k = 0; k < 4; k++){ a2[j][k] = 0.f; a3[j][k] = 0.f; }
    #pragma unroll 4
    for (int j = 0; j < SS; j++){
        float4 hx = *(const float4*)(&svT[j][b0]);
        float2 w2 = *(const float2*)(upd_w2 + j*3*SS + SS   + c0);
        float2 w3 = *(const float2*)(upd_w2 + j*3*SS + 2*SS + c0);
        float ha[4] = {hx.x, hx.y, hx.z, hx.w};
        #pragma unroll
        for (int k = 0; k < 4; k++){
            a2[0][k] = fmaf(ha[k], w2.x, a2[0][k]);
            a2[1][k] = fmaf(ha[k], w2.y, a2[1][k]);
            a3[0][k] = fmaf(ha[k], w3.x, a3[0][k]);
            a3[1][k] = fmaf(ha[k], w3.y, a3[1][k]);
        }
    }
    float2 bsv = *(const float2*)(upd_b2 + SS   + c0);
    float2 bss = *(const float2*)(upd_b2 + 2*SS + c0);
    #pragma unroll
    for (int k = 0; k < 4; k++){
        int g = gIdx[b0+k];
        float ns0 = (a3[0][k] + bss.x) + 3.0f*dreg[k]*(a2[0][k] + bsv.x);
        float ns1 = (a3[1][k] + bss.y) + 3.0f*dreg[k]*(a2[1][k] + bsv.y);
        atomicAdd(&gs[g*SS + c0 + 0], ns0);
        atomicAdd(&gs[g*SS + c0 + 1], ns1);
    }
}

// ---------------------------------------------------------------------------
// Kernel 4: readout per graph
// ---------------------------------------------------------------------------
__global__ __launch_bounds__(128) void k_out(
    const float* __restrict__ gs,
    const float* __restrict__ w1, const float* __restrict__ b1,
    const float* __restrict__ w2, const float* __restrict__ b2,
    float* __restrict__ out){
    __shared__ float gsL[SS];
    __shared__ float red[2];
    int g = blockIdx.x, t = threadIdx.x;
    gsL[t] = gs[g*SS + t];
    __syncthreads();
    float acc = b1[t];
    #pragma unroll 4
    for (int s = 0; s < SS; s++) acc = fmaf(gsL[s], w1[s*SS + t], acc);
    float p = silu_f(acc) * w2[t];
    for (int off = 32; off; off >>= 1) p += __shfl_down(p, off);
    if ((t & 63) == 0) red[t >> 6] = p;
    __syncthreads();
    if (t == 0) out[g] = red[0] + red[1] + b2[0];
}

extern "C" void kernel_launch(void* const* d_in, const int* in_sizes, int n_in,
                              void* d_out, int out_size, void* d_ws, size_t ws_size,
                              hipStream_t stream) {
    const float* evd     = (const float*)d_in[0];
    const float* elen    = (const float*)d_in[1];
    const int*   nfrom   = (const int*)  d_in[2];
    const int*   ngi     = (const int*)  d_in[3];
    const float* emb0    = (const float*)d_in[5];
    const float* phi_w1  = (const float*)d_in[6];
    const float* phi_b1  = (const float*)d_in[7];
    const float* phi_w2  = (const float*)d_in[8];
    const float* phi_b2  = (const float*)d_in[9];
    const float* filt_w  = (const float*)d_in[10];
    const float* filt_b  = (const float*)d_in[11];
    const float* u_w     = (const float*)d_in[12];
    const float* v_w     = (const float*)d_in[13];
    const float* upd_w1  = (const float*)d_in[14];
    const float* upd_b1  = (const float*)d_in[15];
    const float* upd_w2  = (const float*)d_in[16];
    const float* upd_b2  = (const float*)d_in[17];
    const float* out_w1  = (const float*)d_in[18];
    const float* out_b1  = (const float*)d_in[19];
    const float* out_w2  = (const float*)d_in[20];
    const float* out_b2  = (const float*)d_in[21];

    float* ws    = (float*)d_ws;
    float* phiW  = ws;                       // 384 (pad to 512)
    float* state = ws + 512;                 // N*S
    float* sv    = state + NN*SS;            // N*S
    float* gs    = sv + NN*SS;               // G*S
    float* phiH  = gs + GG*SS;               // 128

    k_phi1<<<1, 256, 0, stream>>>(emb0, phi_w1, phi_b1, phiH, gs);
    k_phi2<<<12, 128, 0, stream>>>(phiH, phi_w2, phi_b2, phiW);
    k_edge<<<NN, 64, 0, stream>>>(evd, elen, nfrom, filt_w, filt_b, phiW, state, sv);
    k_update<<<NN/NB, 128, 0, stream>>>(state, sv, u_w, v_w,
                                        upd_w1, upd_b1, upd_w2, upd_b2, ngi, gs);
    k_out<<<GG, 128, 0, stream>>>(gs, out_w1, out_b1, out_w2, out_b2, (float*)d_out);
}